// Round 1
// baseline (172.018 us; speedup 1.0000x reference)
//
#include <hip/hip_runtime.h>

// Morphological dilation2d on MI355X (gfx950).
// out[b,o,h,w] = max_{c,i,j} ( x_zpad[b,c,h+i-2,w+j-2] + weight[o,c,i,j] )
// B=4, C=4, O=4, H=W=1024, K=5, PAD=2, fp32. Zero-padded (pad contributes 0 + w).
//
// Key idea this round: pk-add packs OUTPUT-CHANNEL pairs, not pixel pairs.
//   q = v_pk_add_f32( window_pair, weight_pair )  with op_sel broadcasting the
//   window element to both halves. Weight pairs {w[o0],w[o1]} are naturally
//   aligned in a [c][i][j][o] LDS layout; window pairs are aligned sub-pairs of
//   the ds_read_b128 window. -> zero v_mov marshalling in the hot loop.

constexpr int Himg = 1024, Wimg = 1024, Cin = 4, Cout = 4, Kn = 5;
constexpr int TH = 8, TW = 128;     // output tile per 256-thread block
constexpr int LR = TH + 4;          // 12 LDS rows (halo +-2)
constexpr int LC = TW + 8;          // 136 LDS cols (halo -4..+3, keeps b128 windows aligned)
constexpr int LC4 = LC / 4;         // 34 float4 chunks per row
constexpr int NW = Cout * Cin * Kn * Kn;  // 400 weights

typedef float v2f __attribute__((ext_vector_type(2)));

// d = { x.lo + w.lo , x.lo + w.hi }   (broadcast low element of x-pair)
__device__ __forceinline__ v2f pk_add_lo(v2f xp, v2f wp) {
  v2f d;
  asm("v_pk_add_f32 %0, %1, %2 op_sel:[0,0] op_sel_hi:[0,1]"
      : "=v"(d) : "v"(xp), "v"(wp));
  return d;
}
// d = { x.hi + w.lo , x.hi + w.hi }   (broadcast high element of x-pair)
__device__ __forceinline__ v2f pk_add_hi(v2f xp, v2f wp) {
  v2f d;
  asm("v_pk_add_f32 %0, %1, %2 op_sel:[1,0] op_sel_hi:[1,1]"
      : "=v"(d) : "v"(xp), "v"(wp));
  return d;
}

__global__ __launch_bounds__(256) void morph(const float* __restrict__ x,
                                             const float* __restrict__ w,
                                             float* __restrict__ out) {
  __shared__ __align__(16) float xs[Cin][LR][LC];
  __shared__ __align__(16) float ws[Cin][Kn][Kn][Cout];  // [c][i][j][o] -> o-pairs aligned

  const int tid = threadIdx.x;
  const int tile_w0 = blockIdx.x * TW;
  const int tile_r0 = blockIdx.y * TH;
  const int b = blockIdx.z;

  // ---- stage weights, transposed [o][c][i][j] -> [c][i][j][o] (once per block) ----
  for (int t = tid; t < NW; t += 256) {
    const int o  = t / (Cin * Kn * Kn);
    const int r  = t % (Cin * Kn * Kn);
    const int c  = r / (Kn * Kn);
    const int r2 = r % (Kn * Kn);
    const int i  = r2 / Kn, j = r2 % Kn;
    ws[c][i][j][o] = w[t];
  }

  // ---- stage x tile (+halo, zero pad) into LDS, float4 coalesced ----
  for (int idx = tid; idx < Cin * LR * LC4; idx += 256) {
    const int c   = idx / (LR * LC4);
    const int rem = idx - c * (LR * LC4);
    const int row = rem / LC4;
    const int ch  = rem - row * LC4;
    const int gr  = tile_r0 - 2 + row;
    const int gc  = tile_w0 - 4 + ch * 4;
    float4 v = make_float4(0.f, 0.f, 0.f, 0.f);
    if ((unsigned)gr < (unsigned)Himg) {
      const float* src = x + ((size_t)(b * Cin + c) * Himg + gr) * Wimg;
      if (gc >= 0 && gc <= Wimg - 4) {
        v = *(const float4*)(src + gc);
      } else {
        if ((unsigned)(gc + 0) < (unsigned)Wimg) v.x = src[gc + 0];
        if ((unsigned)(gc + 1) < (unsigned)Wimg) v.y = src[gc + 1];
        if ((unsigned)(gc + 2) < (unsigned)Wimg) v.z = src[gc + 2];
        if ((unsigned)(gc + 3) < (unsigned)Wimg) v.w = src[gc + 3];
      }
    }
    *(float4*)&xs[c][row][ch * 4] = v;
  }
  __syncthreads();

  const int tx = tid & 31;   // 32 thread-cols x 4 px
  const int ty = tid >> 5;   // 8 rows

  // acc pairs: a01[p] = {acc_o0, acc_o1}, a23[p] = {acc_o2, acc_o3} for pixel p
  v2f a01[4], a23[4];
#pragma unroll
  for (int p = 0; p < 4; ++p) {
    a01[p].x = -3.4e38f; a01[p].y = -3.4e38f;
    a23[p].x = -3.4e38f; a23[p].y = -3.4e38f;
  }

#pragma unroll 1
  for (int c = 0; c < Cin; ++c) {
#pragma unroll
    for (int i = 0; i < Kn; ++i) {
      // window values win[2..9] as aligned pairs P[1..4]; P[k] = (win[2k], win[2k+1])
      const float* rowp = &xs[c][ty + i][tx * 4];
      v2f P[5];
      P[1] = *(const v2f*)(rowp + 2);
      P[2] = *(const v2f*)(rowp + 4);
      P[3] = *(const v2f*)(rowp + 6);
      P[4] = *(const v2f*)(rowp + 8);

      // weight pairs for this (c,i): uniform-address LDS reads -> broadcast, no conflict
      const v2f* wp = (const v2f*)&ws[c][i][0][0];
      v2f w01[5], w23[5];
#pragma unroll
      for (int j = 0; j < Kn; ++j) {
        w01[j] = wp[2 * j];       // {w[o0], w[o1]}
        w23[j] = wp[2 * j + 1];   // {w[o2], w[o3]}
      }

#pragma unroll
      for (int p = 0; p < 4; ++p) {
        v2f q01[5], q23[5];
#pragma unroll
        for (int j = 0; j < Kn; ++j) {
          const int idx = 2 + p + j;           // compile-time constant after unroll
          const v2f xp = P[idx >> 1];
          if (idx & 1) {
            q01[j] = pk_add_hi(xp, w01[j]);
            q23[j] = pk_add_hi(xp, w23[j]);
          } else {
            q01[j] = pk_add_lo(xp, w01[j]);
            q23[j] = pk_add_lo(xp, w23[j]);
          }
        }
        // per-o reduce: v_max3(q0,q1,q2), v_max3(q3,q4,acc), v_max -> 3 instrs each
        a01[p].x = fmaxf(fmaxf(fmaxf(q01[0].x, q01[1].x), q01[2].x),
                         fmaxf(fmaxf(q01[3].x, q01[4].x), a01[p].x));
        a01[p].y = fmaxf(fmaxf(fmaxf(q01[0].y, q01[1].y), q01[2].y),
                         fmaxf(fmaxf(q01[3].y, q01[4].y), a01[p].y));
        a23[p].x = fmaxf(fmaxf(fmaxf(q23[0].x, q23[1].x), q23[2].x),
                         fmaxf(fmaxf(q23[3].x, q23[4].x), a23[p].x));
        a23[p].y = fmaxf(fmaxf(fmaxf(q23[0].y, q23[1].y), q23[2].y),
                         fmaxf(fmaxf(q23[3].y, q23[4].y), a23[p].y));
      }
    }
  }

  // ---- epilogue: float4 stores, coalesced ----
  const int r = tile_r0 + ty;
  const int gc0 = tile_w0 + tx * 4;
  {
    float4 r0 = make_float4(a01[0].x, a01[1].x, a01[2].x, a01[3].x);  // o=0
    float4 r1 = make_float4(a01[0].y, a01[1].y, a01[2].y, a01[3].y);  // o=1
    float4 r2 = make_float4(a23[0].x, a23[1].x, a23[2].x, a23[3].x);  // o=2
    float4 r3 = make_float4(a23[0].y, a23[1].y, a23[2].y, a23[3].y);  // o=3
    *(float4*)&out[((size_t)(b * Cout + 0) * Himg + r) * Wimg + gc0] = r0;
    *(float4*)&out[((size_t)(b * Cout + 1) * Himg + r) * Wimg + gc0] = r1;
    *(float4*)&out[((size_t)(b * Cout + 2) * Himg + r) * Wimg + gc0] = r2;
    *(float4*)&out[((size_t)(b * Cout + 3) * Himg + r) * Wimg + gc0] = r3;
  }
}

extern "C" void kernel_launch(void* const* d_in, const int* in_sizes, int n_in,
                              void* d_out, int out_size, void* d_ws, size_t ws_size,
                              hipStream_t stream) {
  const float* x = (const float*)d_in[0];
  const float* w = (const float*)d_in[1];
  float* out = (float*)d_out;

  dim3 grid(Wimg / TW, Himg / TH, 4);  // (8, 128, 4)
  morph<<<grid, dim3(256), 0, stream>>>(x, w, out);
}

// Round 3
// 158.213 us; speedup vs baseline: 1.0873x; 1.0873x over previous
//
#include <hip/hip_runtime.h>

// Morphological dilation2d on MI355X (gfx950).
// out[b,o,h,w] = max_{c,i,j} ( x_zpad[b,c,h+i-2,w+j-2] + weight[o,c,i,j] )
// B=4, C=4, O=4, H=W=1024, K=5, PAD=2, fp32.
//
// Round-3 == round-2 resubmit (bench infra failed; hypothesis untested).
// Structure identical to the measured-75us kernel, but the workspace holds
// DUPLICATED weight pairs wd[c][i][o][j] = {w,w}. The hot loop loads each
// broadcast pair as a wave-uniform aligned v2f -> s_load into an SGPR pair that
// v_pk_add_f32 consumes directly (VOP3P allows one 64-bit SGPR source). This
// deletes the ~40 v_mov broadcast-marshalling instructions per (c,i) (~26% of
// the hot loop's VALU issue).

constexpr int Himg = 1024, Wimg = 1024, Cin = 4, Cout = 4, Kn = 5;
constexpr int TH = 8, TW = 128;     // output tile per 256-thread block
constexpr int LR = TH + 4;          // 12 LDS rows (halo +-2)
constexpr int LC = TW + 8;          // 136 LDS cols (halo -4..+3 for aligned b128 window reads)
constexpr int LC4 = LC / 4;         // 34 float4 chunks per row
constexpr int NW = Cout * Cin * Kn * Kn;  // 400 weights

typedef float v2f __attribute__((ext_vector_type(2)));

// weight [o][c][i][j] -> wd[c][i][o][j] = {w, w}  (duplicated pairs, 3.2 KB)
__global__ void reorg_w(const float* __restrict__ w, float* __restrict__ wd) {
  int idx = threadIdx.x;
  if (idx < NW) {
    int o  = idx / (Cin * Kn * Kn);
    int r  = idx % (Cin * Kn * Kn);
    int c  = r / (Kn * Kn);
    int r2 = r % (Kn * Kn);
    int i  = r2 / Kn, j = r2 % Kn;
    float v = w[idx];
    int d = (((c * Kn + i) * Cout + o) * Kn + j) * 2;
    wd[d + 0] = v;
    wd[d + 1] = v;
  }
}

// 5-input max folded so LLVM forms v_max3_f32.
__device__ __forceinline__ float max5(float a, float b, float c, float d, float e) {
  return fmaxf(fmaxf(a, b), fmaxf(c, fmaxf(d, e)));
}

template <bool DUP>
__global__ __launch_bounds__(256) void morph(const float* __restrict__ x,
                                             const float* __restrict__ wt,
                                             float* __restrict__ out) {
  __shared__ __align__(16) float xs[Cin][LR][LC];
  const int tid = threadIdx.x;
  const int tile_w0 = blockIdx.x * TW;
  const int tile_r0 = blockIdx.y * TH;
  const int b = blockIdx.z;

  // ---- stage x tile (+halo, zero pad) into LDS, float4 coalesced ----
  for (int idx = tid; idx < Cin * LR * LC4; idx += 256) {
    const int c   = idx / (LR * LC4);
    const int rem = idx - c * (LR * LC4);
    const int row = rem / LC4;
    const int ch  = rem - row * LC4;
    const int gr  = tile_r0 - 2 + row;
    const int gc  = tile_w0 - 4 + ch * 4;
    float4 v = make_float4(0.f, 0.f, 0.f, 0.f);
    if ((unsigned)gr < (unsigned)Himg) {
      const float* src = x + ((size_t)(b * Cin + c) * Himg + gr) * Wimg;
      if (gc >= 0 && gc <= Wimg - 4) {
        v = *(const float4*)(src + gc);
      } else {
        if ((unsigned)(gc + 0) < (unsigned)Wimg) v.x = src[gc + 0];
        if ((unsigned)(gc + 1) < (unsigned)Wimg) v.y = src[gc + 1];
        if ((unsigned)(gc + 2) < (unsigned)Wimg) v.z = src[gc + 2];
        if ((unsigned)(gc + 3) < (unsigned)Wimg) v.w = src[gc + 3];
      }
    }
    *(float4*)&xs[c][row][ch * 4] = v;
  }
  __syncthreads();

  const int tx = tid & 31;   // 32 thread-cols x 4 px
  const int ty = tid >> 5;   // 8 rows

  float acc[Cout][4];
#pragma unroll
  for (int o = 0; o < Cout; ++o)
#pragma unroll
    for (int p = 0; p < 4; ++p) acc[o][p] = -3.4e38f;

// Per output-channel O: 10 packed adds (v_pk_add_f32, SGPR-pair weight operand)
// + 4 x (max5 tree + acc fold).
#define ACC_O(O, WPAIR)                                                                   \
  do {                                                                                    \
    v2f p01[5], p23[5];                                                                   \
    _Pragma("unroll") for (int j = 0; j < 5; ++j) {                                       \
      v2f wb = WPAIR;                                                                     \
      p01[j] = a2[j] + wb;                                                                \
      p23[j] = b2[j] + wb;                                                                \
    }                                                                                     \
    acc[O][0] = fmaxf(acc[O][0], max5(p01[0].x, p01[1].x, p01[2].x, p01[3].x, p01[4].x)); \
    acc[O][1] = fmaxf(acc[O][1], max5(p01[0].y, p01[1].y, p01[2].y, p01[3].y, p01[4].y)); \
    acc[O][2] = fmaxf(acc[O][2], max5(p23[0].x, p23[1].x, p23[2].x, p23[3].x, p23[4].x)); \
    acc[O][3] = fmaxf(acc[O][3], max5(p23[0].y, p23[1].y, p23[2].y, p23[3].y, p23[4].y)); \
  } while (0)

#pragma unroll 1
  for (int c = 0; c < Cin; ++c) {
#pragma unroll
    for (int i = 0; i < Kn; ++i) {
      const float* rowp = &xs[c][ty + i][tx * 4];
      float4 q0 = *(const float4*)(rowp);
      float4 q1 = *(const float4*)(rowp + 4);
      float4 q2 = *(const float4*)(rowp + 8);
      float win[12] = {q0.x, q0.y, q0.z, q0.w, q1.x, q1.y, q1.z, q1.w,
                       q2.x, q2.y, q2.z, q2.w};

      // window pairs, shared across the 4 output channels
      v2f a2[5], b2[5];
#pragma unroll
      for (int j = 0; j < 5; ++j) {
        a2[j].x = win[2 + j]; a2[j].y = win[3 + j];
        b2[j].x = win[4 + j]; b2[j].y = win[5 + j];
      }

      if (DUP) {
        // wave-uniform duplicated pairs -> SGPR pairs feeding v_pk_add_f32
        const v2f* wdp = (const v2f*)wt + ((c * Kn + i) * Cout) * Kn;
        ACC_O(0, wdp[0 * Kn + j]);
        ACC_O(1, wdp[1 * Kn + j]);
        ACC_O(2, wdp[2 * Kn + j]);
        ACC_O(3, wdp[3 * Kn + j]);
      } else {
        float wo0[5], wo1[5], wo2[5], wo3[5];
#pragma unroll
        for (int j = 0; j < Kn; ++j) {
          wo0[j] = wt[((0 * Cin + c) * Kn + i) * Kn + j];
          wo1[j] = wt[((1 * Cin + c) * Kn + i) * Kn + j];
          wo2[j] = wt[((2 * Cin + c) * Kn + i) * Kn + j];
          wo3[j] = wt[((3 * Cin + c) * Kn + i) * Kn + j];
        }
        ACC_O(0, (v2f{wo0[j], wo0[j]}));
        ACC_O(1, (v2f{wo1[j], wo1[j]}));
        ACC_O(2, (v2f{wo2[j], wo2[j]}));
        ACC_O(3, (v2f{wo3[j], wo3[j]}));
      }
    }
  }
#undef ACC_O

  // ---- epilogue: float4 stores, coalesced ----
  const int r = tile_r0 + ty;
  const int gc0 = tile_w0 + tx * 4;
#pragma unroll
  for (int o = 0; o < Cout; ++o) {
    float4 res = make_float4(acc[o][0], acc[o][1], acc[o][2], acc[o][3]);
    *(float4*)&out[((size_t)(b * Cout + o) * Himg + r) * Wimg + gc0] = res;
  }
}

extern "C" void kernel_launch(void* const* d_in, const int* in_sizes, int n_in,
                              void* d_out, int out_size, void* d_ws, size_t ws_size,
                              hipStream_t stream) {
  const float* x = (const float*)d_in[0];
  const float* w = (const float*)d_in[1];
  float* out = (float*)d_out;

  dim3 grid(Wimg / TW, Himg / TH, 4);  // (8, 128, 4)

  if (ws_size >= sizeof(float) * 2 * NW) {
    float* wd = (float*)d_ws;
    reorg_w<<<dim3(1), dim3(512), 0, stream>>>(w, wd);
    morph<true><<<grid, dim3(256), 0, stream>>>(x, wd, out);
  } else {
    morph<false><<<grid, dim3(256), 0, stream>>>(x, w, out);
  }
}